// Round 13
// baseline (381.533 us; speedup 1.0000x reference)
//
#include <hip/hip_runtime.h>

#define NN 20000     // nodes
#define NE 320000    // edges
#define NG 64        // graphs
#define DIN 128
#define DH 64
#define NH 8
#define HD 512       // NH*DH
#define NC 32

typedef unsigned short ushort_t;
typedef unsigned int uint_t;

__device__ __forceinline__ ushort_t f2bf(float f) {   // RNE float->bf16
  uint_t x = __float_as_uint(f);
  uint_t r = (x + 0x7fffu + ((x >> 16) & 1u)) >> 16;
  return (ushort_t)r;
}

template<int PAT>
__device__ __forceinline__ float swz(float v) {
  return __int_as_float(__builtin_amdgcn_ds_swizzle(__float_as_int(v), PAT));
}

// ---------- input linear tile: 16 rows of [NN,128]@[128,64]+b (256 thr) ----------
__device__ __forceinline__ void gemm_in_tile(const float* __restrict__ gf,
    const float* __restrict__ W_in, const float* __restrict__ b_in,
    float* __restrict__ h0, int tile) {
  __shared__ float AsIn[16][DIN];
  const int t = threadIdx.x;
  const int row0 = tile * 16;                 // 1250*16 == 20000 exact
  for (int i = t; i < 16 * DIN; i += 256)
    AsIn[i >> 7][i & 127] = gf[(size_t)(row0 + (i >> 7)) * DIN + (i & 127)];
  __syncthreads();
  const int c = t & 63, rg = t >> 6;          // 4 rows per thread
  float acc[4] = {0.f, 0.f, 0.f, 0.f};
  for (int k = 0; k < DIN; ++k) {
    float w = W_in[k * DH + c];
#pragma unroll
    for (int i = 0; i < 4; ++i) acc[i] += AsIn[rg * 4 + i][k] * w;
  }
  float b = b_in[c];
#pragma unroll
  for (int i = 0; i < 4; ++i)
    h0[(size_t)(row0 + rg * 4 + i) * DH + c] = acc[i] + b;
}

// ---------- hidden linear tile: 32 rows x 512 cols, 1 col/thread (512 thr) -------
// W element read ONCE per block; As float4-chunked -> ds_read_b128 broadcasts.
#define ROWS_P 32
#define TPM 625                               // 20000/32 blocks per matrix
__device__ __forceinline__ void pair_tile(const float* __restrict__ A,
    const float* __restrict__ Ws, const float* __restrict__ bs,
    const float* __restrict__ Wd, const float* __restrict__ bd,
    ushort_t* __restrict__ fsb, float* __restrict__ fd, int tile) {
  __shared__ float4 AsP4[ROWS_P][16];         // 32 rows x 64 k = 8 KB
  const int t = threadIdx.x;                  // 0..511
  const bool isFd = tile >= TPM;
  const int bx = isFd ? tile - TPM : tile;
  const float* W = isFd ? Wd : Ws;
  const float* b = isFd ? bd : bs;
  const int row0 = bx * ROWS_P;
  {                                           // 512 float4 slots, 1 per thread
    int row = t >> 4, kq = t & 15;
    AsP4[row][kq] = *(const float4*)&A[(size_t)(row0 + row) * DH + 4 * kq];
  }
  __syncthreads();
  const int c = t;                            // one output column per thread
  float acc[ROWS_P];
#pragma unroll
  for (int r = 0; r < ROWS_P; ++r) acc[r] = 0.f;
  for (int kb = 0; kb < 16; ++kb) {
    float w0 = W[(size_t)(4 * kb + 0) * HD + c];
    float w1 = W[(size_t)(4 * kb + 1) * HD + c];
    float w2 = W[(size_t)(4 * kb + 2) * HD + c];
    float w3 = W[(size_t)(4 * kb + 3) * HD + c];
#pragma unroll
    for (int r = 0; r < ROWS_P; ++r) {
      float4 a = AsP4[r][kb];
      acc[r] = fmaf(a.x, w0, fmaf(a.y, w1, fmaf(a.z, w2, fmaf(a.w, w3, acc[r]))));
    }
  }
  float bv = b[c];
  if (!isFd) {
#pragma unroll
    for (int r = 0; r < ROWS_P; ++r)
      fsb[(size_t)(row0 + r) * HD + c] = f2bf(acc[r] + bv);
  } else {
#pragma unroll
    for (int r = 0; r < ROWS_P; ++r)
      fd[(size_t)(row0 + r) * HD + c] = acc[r] + bv;
  }
}

// ---------- P0: blocks 0..1249 input GEMM | 1250..2499 hist | 2500.. gbound ------
__global__ __launch_bounds__(256) void k_pre(const float* __restrict__ gf,
    const float* __restrict__ W_in, const float* __restrict__ b_in,
    float* __restrict__ h0, const int* __restrict__ dst, int* __restrict__ counts,
    const int* __restrict__ gid, int* __restrict__ gs) {
  const int bid = blockIdx.x;
  const int NB_IN = NN / 16;                  // 1250
  if (bid < NB_IN) {
    gemm_in_tile(gf, W_in, b_in, h0, bid);
  } else if (bid < NB_IN + NE / 256) {
    int e = (bid - NB_IN) * 256 + threadIdx.x;
    atomicAdd(&counts[dst[e]], 1);
  } else {
    int i = (bid - (NB_IN + NE / 256)) * 256 + threadIdx.x;
    if (i > NN) return;
    if (i == 0) {
      for (int g = 0; g <= gid[0]; ++g) gs[g] = 0;
    } else if (i == NN) {
      for (int g = gid[NN - 1] + 1; g <= NG; ++g) gs[g] = NN;
    } else {
      int a = gid[i - 1], b2 = gid[i];
      for (int g = a + 1; g <= b2; ++g) gs[g] = i;
    }
  }
}

// ---------- parallel CSR segment assignment (wave scan + 1 atomic/wave) ----------
__global__ __launch_bounds__(256) void k_assign(const int* __restrict__ counts,
    int* __restrict__ row_beg, int* __restrict__ row_end, int* __restrict__ cursor,
    int* __restrict__ gcounter) {
  const int i = blockIdx.x * 256 + threadIdx.x;
  const int lane = threadIdx.x & 63;
  int cnt = (i < NN) ? counts[i] : 0;
  int pre = cnt;                              // inclusive scan over 64 lanes
#pragma unroll
  for (int d = 1; d < 64; d <<= 1) {
    int o = __shfl_up(pre, d);
    if (lane >= d) pre += o;
  }
  int total = __shfl(pre, 63);
  int excl = pre - cnt;
  int base = 0;
  if (lane == 63 && total > 0) base = atomicAdd(gcounter, total);
  base = __shfl(base, 63);
  if (i < NN) {
    int b = base + excl;
    row_beg[i] = b;
    row_end[i] = b + cnt;
    cursor[i] = b;
  }
}

// ---------- P3: blocks 0..1249 layer-1 GEMM pair | 1250..1874 CSR scatter --------
__global__ __launch_bounds__(512) void k_scatpair(const float* __restrict__ A,
    const float* __restrict__ Ws, const float* __restrict__ bs,
    const float* __restrict__ Wd, const float* __restrict__ bd,
    ushort_t* __restrict__ fsb, float* __restrict__ fd,
    const int* __restrict__ dst, const int* __restrict__ src,
    int* __restrict__ cursor, int* __restrict__ src_sorted) {
  const int bid = blockIdx.x;
  if (bid < 2 * TPM) {
    pair_tile(A, Ws, bs, Wd, bd, fsb, fd, bid);
  } else {
    int e = (bid - 2 * TPM) * 512 + threadIdx.x;
    int p = atomicAdd(&cursor[dst[e]], 1);
    src_sorted[p] = src[e];
  }
}

// ---------- layer-2 GEMM pair ----------
__global__ __launch_bounds__(512) void k_pair(const float* __restrict__ A,
    const float* __restrict__ Ws, const float* __restrict__ bs,
    const float* __restrict__ Wd, const float* __restrict__ bd,
    ushort_t* __restrict__ fsb, float* __restrict__ fd) {
  pair_tile(A, Ws, bs, Wd, bd, fsb, fd, blockIdx.x);
}

// ---------- fused GATv2: ONE WAVE PER NODE, lane = 8 contiguous bf16 feats --------
// 4-edge unroll: shared online-softmax rescale + 4 outstanding gathers.
__global__ __launch_bounds__(256) void k_gat(const ushort_t* __restrict__ fsb,
    const float* __restrict__ fd, const int* __restrict__ src_sorted,
    const int* __restrict__ row_beg, const int* __restrict__ row_end,
    const float* __restrict__ attn, const float* __restrict__ bias,
    float* __restrict__ hout, int do_relu) {
  const int lane = threadIdx.x & 63;
  const int v = blockIdx.x * 4 + (threadIdx.x >> 6);
  const int fi = lane * 8;                    // head = lane>>3
  float fdv[8], av[8];
  *(float4*)&fdv[0] = *(const float4*)&fd[(size_t)v * HD + fi];
  *(float4*)&fdv[4] = *(const float4*)&fd[(size_t)v * HD + fi + 4];
  *(float4*)&av[0]  = *(const float4*)&attn[fi];
  *(float4*)&av[4]  = *(const float4*)&attn[fi + 4];
  int e = row_beg[v];
  const int end = row_end[v];
  float m = -3.4e38f, sum = 0.f;
  float acc[8];
#pragma unroll
  for (int i = 0; i < 8; ++i) acc[i] = 0.f;
  for (; e + 3 < end; e += 4) {               // 4 edges per iter
    int sA = src_sorted[e],     sB = src_sorted[e + 1];
    int sC = src_sorted[e + 2], sD = src_sorted[e + 3];
    uint4 uA = *(const uint4*)&fsb[(size_t)sA * HD + fi];
    uint4 uB = *(const uint4*)&fsb[(size_t)sB * HD + fi];
    uint4 uC = *(const uint4*)&fsb[(size_t)sC * HD + fi];
    uint4 uD = *(const uint4*)&fsb[(size_t)sD * HD + fi];
    float fA[8], fB[8], fC[8], fD[8];
    fA[0] = __uint_as_float(uA.x << 16); fA[1] = __uint_as_float(uA.x & 0xffff0000u);
    fA[2] = __uint_as_float(uA.y << 16); fA[3] = __uint_as_float(uA.y & 0xffff0000u);
    fA[4] = __uint_as_float(uA.z << 16); fA[5] = __uint_as_float(uA.z & 0xffff0000u);
    fA[6] = __uint_as_float(uA.w << 16); fA[7] = __uint_as_float(uA.w & 0xffff0000u);
    fB[0] = __uint_as_float(uB.x << 16); fB[1] = __uint_as_float(uB.x & 0xffff0000u);
    fB[2] = __uint_as_float(uB.y << 16); fB[3] = __uint_as_float(uB.y & 0xffff0000u);
    fB[4] = __uint_as_float(uB.z << 16); fB[5] = __uint_as_float(uB.z & 0xffff0000u);
    fB[6] = __uint_as_float(uB.w << 16); fB[7] = __uint_as_float(uB.w & 0xffff0000u);
    fC[0] = __uint_as_float(uC.x << 16); fC[1] = __uint_as_float(uC.x & 0xffff0000u);
    fC[2] = __uint_as_float(uC.y << 16); fC[3] = __uint_as_float(uC.y & 0xffff0000u);
    fC[4] = __uint_as_float(uC.z << 16); fC[5] = __uint_as_float(uC.z & 0xffff0000u);
    fC[6] = __uint_as_float(uC.w << 16); fC[7] = __uint_as_float(uC.w & 0xffff0000u);
    fD[0] = __uint_as_float(uD.x << 16); fD[1] = __uint_as_float(uD.x & 0xffff0000u);
    fD[2] = __uint_as_float(uD.y << 16); fD[3] = __uint_as_float(uD.y & 0xffff0000u);
    fD[4] = __uint_as_float(uD.z << 16); fD[5] = __uint_as_float(uD.z & 0xffff0000u);
    fD[6] = __uint_as_float(uD.w << 16); fD[7] = __uint_as_float(uD.w & 0xffff0000u);
    float pA = 0.f, pB = 0.f, pC = 0.f, pD = 0.f;
#pragma unroll
    for (int i = 0; i < 8; ++i) {
      float xA = fA[i] + fdv[i];
      pA = fmaf(av[i], fmaxf(xA, 0.f) + 0.2f * fminf(xA, 0.f), pA);
      float xB = fB[i] + fdv[i];
      pB = fmaf(av[i], fmaxf(xB, 0.f) + 0.2f * fminf(xB, 0.f), pB);
      float xC = fC[i] + fdv[i];
      pC = fmaf(av[i], fmaxf(xC, 0.f) + 0.2f * fminf(xC, 0.f), pC);
      float xD = fD[i] + fdv[i];
      pD = fmaf(av[i], fmaxf(xD, 0.f) + 0.2f * fminf(xD, 0.f), pD);
    }
    pA += swz<0x041F>(pA); pB += swz<0x041F>(pB); pC += swz<0x041F>(pC); pD += swz<0x041F>(pD);
    pA += swz<0x081F>(pA); pB += swz<0x081F>(pB); pC += swz<0x081F>(pC); pD += swz<0x081F>(pD);
    pA += swz<0x101F>(pA); pB += swz<0x101F>(pB); pC += swz<0x101F>(pC); pD += swz<0x101F>(pD);
    float mn = fmaxf(fmaxf(m, fmaxf(pA, pB)), fmaxf(pC, pD));
    float scale = __expf(m - mn);
    float wA = __expf(pA - mn), wB = __expf(pB - mn);
    float wC = __expf(pC - mn), wD = __expf(pD - mn);
    sum = fmaf(sum, scale, (wA + wB) + (wC + wD));
#pragma unroll
    for (int i = 0; i < 8; ++i)
      acc[i] = fmaf(acc[i], scale,
                    fmaf(wA, fA[i], fmaf(wB, fB[i], fmaf(wC, fC[i], wD * fD[i]))));
    m = mn;
  }
  for (; e < end; ++e) {                      // 0-3 tail edges (wave-uniform)
    int sA = src_sorted[e];
    uint4 uA = *(const uint4*)&fsb[(size_t)sA * HD + fi];
    float fA[8];
    fA[0] = __uint_as_float(uA.x << 16); fA[1] = __uint_as_float(uA.x & 0xffff0000u);
    fA[2] = __uint_as_float(uA.y << 16); fA[3] = __uint_as_float(uA.y & 0xffff0000u);
    fA[4] = __uint_as_float(uA.z << 16); fA[5] = __uint_as_float(uA.z & 0xffff0000u);
    fA[6] = __uint_as_float(uA.w << 16); fA[7] = __uint_as_float(uA.w & 0xffff0000u);
    float pA = 0.f;
#pragma unroll
    for (int i = 0; i < 8; ++i) {
      float xA = fA[i] + fdv[i];
      pA = fmaf(av[i], fmaxf(xA, 0.f) + 0.2f * fminf(xA, 0.f), pA);
    }
    pA += swz<0x041F>(pA);
    pA += swz<0x081F>(pA);
    pA += swz<0x101F>(pA);
    float mn = fmaxf(m, pA);
    float scale = __expf(m - mn);
    float wA = __expf(pA - mn);
    sum = fmaf(sum, scale, wA);
#pragma unroll
    for (int i = 0; i < 8; ++i)
      acc[i] = fmaf(acc[i], scale, wA * fA[i]);
    m = mn;
  }
  float inv = 1.f / fmaxf(sum, 1e-9f);
  float outv[8];
#pragma unroll
  for (int i = 0; i < 8; ++i) outv[i] = fmaf(acc[i], inv, bias[fi + i]);
  // head-mean: sum across stride-8 lanes (same feat class), then /8
#pragma unroll
  for (int i = 0; i < 8; ++i) {
    outv[i] += swz<0x201F>(outv[i]);          // xor 8
    outv[i] += swz<0x401F>(outv[i]);          // xor 16
    outv[i] += __shfl_xor(outv[i], 32);
    outv[i] *= 0.125f;
    if (do_relu) outv[i] = fmaxf(outv[i], 0.f);
  }
  if (lane < 8) {                             // lane c holds feats 8c..8c+7
    *(float4*)&hout[(size_t)v * DH + lane * 8]     = make_float4(outv[0], outv[1], outv[2], outv[3]);
    *(float4*)&hout[(size_t)v * DH + lane * 8 + 4] = make_float4(outv[4], outv[5], outv[6], outv[7]);
  }
}

// ---------- per-graph mean + MLP head + softmax ----------
__global__ __launch_bounds__(256) void k_head(const float* __restrict__ h2,
    const int* __restrict__ gsv, const float* __restrict__ Wh1,
    const float* __restrict__ bh1, const float* __restrict__ Wh2,
    const float* __restrict__ bh2, float* __restrict__ out) {
  __shared__ float part[4][DH];
  __shared__ float hg[DH];
  __shared__ float hid[DH];
  __shared__ float logits[NC];
  const int g = blockIdx.x;
  const int t = threadIdx.x;
  const int f = t & 63, chunk = t >> 6;
  int start = gsv[g], stop = gsv[g + 1];
  float s = 0.f;
  for (int r = start + chunk; r < stop; r += 4) s += h2[(size_t)r * DH + f];
  part[chunk][f] = s;
  __syncthreads();
  if (t < DH) {
    float tot = part[0][t] + part[1][t] + part[2][t] + part[3][t];
    hg[t] = tot / fmaxf((float)(stop - start), 1.f);
  }
  __syncthreads();
  if (t < DH) {
    float a = 0.f;
    for (int k = 0; k < DH; ++k) a += hg[k] * Wh1[k * DH + t];
    hid[t] = fmaxf(a + bh1[t], 0.f);
  }
  __syncthreads();
  if (t < NC) {
    float l = 0.f;
    for (int k = 0; k < DH; ++k) l += hid[k] * Wh2[k * NC + t];
    logits[t] = l + bh2[t];
  }
  __syncthreads();
  if (t == 0) {
    float mx = logits[0];
    for (int i = 1; i < NC; ++i) mx = fmaxf(mx, logits[i]);
    float sm = 0.f;
    for (int i = 0; i < NC; ++i) {
      float wv = __expf(logits[i] - mx);
      logits[i] = wv;
      sm += wv;
    }
    float inv = 1.f / sm;
    for (int i = 0; i < NC; ++i) out[g * NC + i] = logits[i] * inv;
  }
}

extern "C" void kernel_launch(void* const* d_in, const int* in_sizes, int n_in,
                              void* d_out, int out_size, void* d_ws, size_t ws_size,
                              hipStream_t stream) {
  const float* g_feats = (const float*)d_in[0];
  const int*   src     = (const int*)d_in[1];
  const int*   dst     = (const int*)d_in[2];
  const int*   gid     = (const int*)d_in[3];
  const float* W_in    = (const float*)d_in[4];
  const float* b_in    = (const float*)d_in[5];
  const float* Wsrc1   = (const float*)d_in[6];
  const float* bsrc1   = (const float*)d_in[7];
  const float* Wdst1   = (const float*)d_in[8];
  const float* bdst1   = (const float*)d_in[9];
  const float* attn1   = (const float*)d_in[10];
  const float* bias1   = (const float*)d_in[11];
  const float* Wsrc2   = (const float*)d_in[12];
  const float* bsrc2   = (const float*)d_in[13];
  const float* Wdst2   = (const float*)d_in[14];
  const float* bdst2   = (const float*)d_in[15];
  const float* attn2   = (const float*)d_in[16];
  const float* bias2   = (const float*)d_in[17];
  const float* Wh1     = (const float*)d_in[18];
  const float* bh1     = (const float*)d_in[19];
  const float* Wh2     = (const float*)d_in[20];
  const float* bh2     = (const float*)d_in[21];

  char* ws = (char*)d_ws;
  size_t off = 0;
  auto A = [&](size_t bytes) -> char* {
    char* q = ws + off;
    off = (off + bytes + 255) & ~(size_t)255;
    return q;
  };
  float*    h0         = (float*)A((size_t)NN * DH * 4);
  float*    h1         = (float*)A((size_t)NN * DH * 4);
  float*    h2         = (float*)A((size_t)NN * DH * 4);
  ushort_t* fsb        = (ushort_t*)A((size_t)NN * HD * 2);
  float*    fd         = (float*)A((size_t)NN * HD * 4);
  int*      row_beg    = (int*)A((size_t)NN * 4);
  int*      row_end    = (int*)A((size_t)NN * 4);
  int*      cursor     = (int*)A((size_t)NN * 4);
  int*      src_sorted = (int*)A((size_t)NE * 4);
  int*      gs         = (int*)A((size_t)(NG + 1) * 4);
  int*      counts     = (int*)A((size_t)(NN + 1) * 4);  // +1: gcounter at [NN]

  const int NB_IN = NN / 16;                  // 1250
  const int histb = NE / 256;                 // 1250
  const int gbb = (NN + 256) / 256;           // 79
  const int scatb = NE / 512;                 // 625

  hipMemsetAsync(counts, 0, (size_t)(NN + 1) * 4, stream);

  k_pre<<<NB_IN + histb + gbb, 256, 0, stream>>>(g_feats, W_in, b_in, h0,
                                                 dst, counts, gid, gs);
  k_assign<<<(NN + 255) / 256, 256, 0, stream>>>(counts, row_beg, row_end,
                                                 cursor, &counts[NN]);
  k_scatpair<<<2 * TPM + scatb, 512, 0, stream>>>(h0, Wsrc1, bsrc1, Wdst1, bdst1,
                                                  fsb, fd, dst, src, cursor, src_sorted);
  k_gat<<<NN / 4, 256, 0, stream>>>(fsb, fd, src_sorted, row_beg, row_end,
                                    attn1, bias1, h1, 1);
  k_pair<<<2 * TPM, 512, 0, stream>>>(h1, Wsrc2, bsrc2, Wdst2, bdst2, fsb, fd);
  k_gat<<<NN / 4, 256, 0, stream>>>(fsb, fd, src_sorted, row_beg, row_end,
                                    attn2, bias2, h2, 0);
  k_head<<<NG, 256, 0, stream>>>(h2, gs, Wh1, bh1, Wh2, bh2, (float*)d_out);
}

// Round 14
// 352.227 us; speedup vs baseline: 1.0832x; 1.0832x over previous
//
#include <hip/hip_runtime.h>

#define NN 20000     // nodes
#define NE 320000    // edges
#define NG 64        // graphs
#define DIN 128
#define DH 64
#define NH 8
#define HD 512       // NH*DH
#define NC 32

typedef unsigned short ushort_t;
typedef unsigned int uint_t;

__device__ __forceinline__ ushort_t f2bf(float f) {   // RNE float->bf16
  uint_t x = __float_as_uint(f);
  uint_t r = (x + 0x7fffu + ((x >> 16) & 1u)) >> 16;
  return (ushort_t)r;
}

template<int PAT>
__device__ __forceinline__ float swz(float v) {
  return __int_as_float(__builtin_amdgcn_ds_swizzle(__float_as_int(v), PAT));
}

// ---------- input linear tile: 16 rows of [NN,128]@[128,64]+b (256 thr) ----------
__device__ __forceinline__ void gemm_in_tile(const float* __restrict__ gf,
    const float* __restrict__ W_in, const float* __restrict__ b_in,
    float* __restrict__ h0, int tile) {
  __shared__ float AsIn[16][DIN];
  const int t = threadIdx.x;
  const int row0 = tile * 16;                 // 1250*16 == 20000 exact
  for (int i = t; i < 16 * DIN; i += 256)
    AsIn[i >> 7][i & 127] = gf[(size_t)(row0 + (i >> 7)) * DIN + (i & 127)];
  __syncthreads();
  const int c = t & 63, rg = t >> 6;          // 4 rows per thread
  float acc[4] = {0.f, 0.f, 0.f, 0.f};
  for (int k = 0; k < DIN; ++k) {
    float w = W_in[k * DH + c];
#pragma unroll
    for (int i = 0; i < 4; ++i) acc[i] += AsIn[rg * 4 + i][k] * w;
  }
  float b = b_in[c];
#pragma unroll
  for (int i = 0; i < 4; ++i)
    h0[(size_t)(row0 + rg * 4 + i) * DH + c] = acc[i] + b;
}

// ---------- hidden linear tile: 32 rows x 512 cols (512 thr, 8x4 per thread) -----
// As float4-staged (128 ds_read_b128/thread), W read by 4 threads/elem via L2.
#define ROWS_P 32
#define TPM 625                               // 20000/32 blocks per matrix
__device__ __forceinline__ void pair_tile(const float* __restrict__ A,
    const float* __restrict__ Ws, const float* __restrict__ bs,
    const float* __restrict__ Wd, const float* __restrict__ bd,
    ushort_t* __restrict__ fsb, float* __restrict__ fd, int tile) {
  __shared__ float4 AsP4[ROWS_P][16];         // 32 rows x 64 k = 8 KB
  const int t = threadIdx.x;                  // 0..511
  const bool isFd = tile >= TPM;
  const int bx = isFd ? tile - TPM : tile;
  const float* W = isFd ? Wd : Ws;
  const float* b = isFd ? bd : bs;
  const int row0 = bx * ROWS_P;
  {                                           // 512 float4 slots, 1 per thread
    int row = t >> 4, kq = t & 15;
    AsP4[row][kq] = *(const float4*)&A[(size_t)(row0 + row) * DH + 4 * kq];
  }
  __syncthreads();
  const int tc = t & 127;                     // cols 4*tc..4*tc+3
  const int tr = t >> 7;                      // rows tr*8..tr*8+7
  float acc[8][4];
#pragma unroll
  for (int r = 0; r < 8; ++r)
#pragma unroll
    for (int c = 0; c < 4; ++c) acc[r][c] = 0.f;
  for (int kb = 0; kb < 16; ++kb) {
    float4 w0 = *(const float4*)&W[(size_t)(4 * kb + 0) * HD + 4 * tc];
    float4 w1 = *(const float4*)&W[(size_t)(4 * kb + 1) * HD + 4 * tc];
    float4 w2 = *(const float4*)&W[(size_t)(4 * kb + 2) * HD + 4 * tc];
    float4 w3 = *(const float4*)&W[(size_t)(4 * kb + 3) * HD + 4 * tc];
#pragma unroll
    for (int r = 0; r < 8; ++r) {
      float4 a = AsP4[tr * 8 + r][kb];
      acc[r][0] = fmaf(a.x, w0.x, fmaf(a.y, w1.x, fmaf(a.z, w2.x, fmaf(a.w, w3.x, acc[r][0]))));
      acc[r][1] = fmaf(a.x, w0.y, fmaf(a.y, w1.y, fmaf(a.z, w2.y, fmaf(a.w, w3.y, acc[r][1]))));
      acc[r][2] = fmaf(a.x, w0.z, fmaf(a.y, w1.z, fmaf(a.z, w2.z, fmaf(a.w, w3.z, acc[r][2]))));
      acc[r][3] = fmaf(a.x, w0.w, fmaf(a.y, w1.w, fmaf(a.z, w2.w, fmaf(a.w, w3.w, acc[r][3]))));
    }
  }
  float4 bv = *(const float4*)&b[4 * tc];
#pragma unroll
  for (int r = 0; r < 8; ++r) {
    int row = row0 + tr * 8 + r;               // 20000 % 32 == 0, always in range
    float v0 = acc[r][0] + bv.x, v1 = acc[r][1] + bv.y;
    float v2 = acc[r][2] + bv.z, v3 = acc[r][3] + bv.w;
    if (!isFd) {
      ushort4 o;
      o.x = f2bf(v0); o.y = f2bf(v1); o.z = f2bf(v2); o.w = f2bf(v3);
      *(ushort4*)&fsb[(size_t)row * HD + 4 * tc] = o;
    } else {
      *(float4*)&fd[(size_t)row * HD + 4 * tc] = make_float4(v0, v1, v2, v3);
    }
  }
}

// ---------- P0: blocks 0..1249 input GEMM | 1250..2499 hist | 2500.. gbound ------
__global__ __launch_bounds__(256) void k_pre(const float* __restrict__ gf,
    const float* __restrict__ W_in, const float* __restrict__ b_in,
    float* __restrict__ h0, const int* __restrict__ dst, int* __restrict__ counts,
    const int* __restrict__ gid, int* __restrict__ gs) {
  const int bid = blockIdx.x;
  const int NB_IN = NN / 16;                  // 1250
  if (bid < NB_IN) {
    gemm_in_tile(gf, W_in, b_in, h0, bid);
  } else if (bid < NB_IN + NE / 256) {
    int e = (bid - NB_IN) * 256 + threadIdx.x;
    atomicAdd(&counts[dst[e]], 1);
  } else {
    int i = (bid - (NB_IN + NE / 256)) * 256 + threadIdx.x;
    if (i > NN) return;
    if (i == 0) {
      for (int g = 0; g <= gid[0]; ++g) gs[g] = 0;
    } else if (i == NN) {
      for (int g = gid[NN - 1] + 1; g <= NG; ++g) gs[g] = NN;
    } else {
      int a = gid[i - 1], b2 = gid[i];
      for (int g = a + 1; g <= b2; ++g) gs[g] = i;
    }
  }
}

// ---------- parallel CSR segment assignment (wave scan + 1 atomic/wave) ----------
__global__ __launch_bounds__(256) void k_assign(const int* __restrict__ counts,
    int* __restrict__ row_beg, int* __restrict__ row_end, int* __restrict__ cursor,
    int* __restrict__ gcounter) {
  const int i = blockIdx.x * 256 + threadIdx.x;
  const int lane = threadIdx.x & 63;
  int cnt = (i < NN) ? counts[i] : 0;
  int pre = cnt;                              // inclusive scan over 64 lanes
#pragma unroll
  for (int d = 1; d < 64; d <<= 1) {
    int o = __shfl_up(pre, d);
    if (lane >= d) pre += o;
  }
  int total = __shfl(pre, 63);
  int excl = pre - cnt;
  int base = 0;
  if (lane == 63 && total > 0) base = atomicAdd(gcounter, total);
  base = __shfl(base, 63);
  if (i < NN) {
    int b = base + excl;
    row_beg[i] = b;
    row_end[i] = b + cnt;
    cursor[i] = b;
  }
}

// ---------- P3: blocks 0..1249 layer-1 GEMM pair | 1250..1874 CSR scatter --------
__global__ __launch_bounds__(512) void k_scatpair(const float* __restrict__ A,
    const float* __restrict__ Ws, const float* __restrict__ bs,
    const float* __restrict__ Wd, const float* __restrict__ bd,
    ushort_t* __restrict__ fsb, float* __restrict__ fd,
    const int* __restrict__ dst, const int* __restrict__ src,
    int* __restrict__ cursor, int* __restrict__ src_sorted) {
  const int bid = blockIdx.x;
  if (bid < 2 * TPM) {
    pair_tile(A, Ws, bs, Wd, bd, fsb, fd, bid);
  } else {
    int e = (bid - 2 * TPM) * 512 + threadIdx.x;
    int p = atomicAdd(&cursor[dst[e]], 1);
    src_sorted[p] = src[e];
  }
}

// ---------- layer-2 GEMM pair ----------
__global__ __launch_bounds__(512) void k_pair(const float* __restrict__ A,
    const float* __restrict__ Ws, const float* __restrict__ bs,
    const float* __restrict__ Wd, const float* __restrict__ bd,
    ushort_t* __restrict__ fsb, float* __restrict__ fd) {
  pair_tile(A, Ws, bs, Wd, bd, fsb, fd, blockIdx.x);
}

// ---------- fused GATv2: ONE WAVE PER NODE, lane = 8 contiguous bf16 feats --------
// 4-edge unroll: shared online-softmax rescale + 4 outstanding gathers.
__global__ __launch_bounds__(256) void k_gat(const ushort_t* __restrict__ fsb,
    const float* __restrict__ fd, const int* __restrict__ src_sorted,
    const int* __restrict__ row_beg, const int* __restrict__ row_end,
    const float* __restrict__ attn, const float* __restrict__ bias,
    float* __restrict__ hout, int do_relu) {
  const int lane = threadIdx.x & 63;
  const int v = blockIdx.x * 4 + (threadIdx.x >> 6);
  const int fi = lane * 8;                    // head = lane>>3
  float fdv[8], av[8];
  *(float4*)&fdv[0] = *(const float4*)&fd[(size_t)v * HD + fi];
  *(float4*)&fdv[4] = *(const float4*)&fd[(size_t)v * HD + fi + 4];
  *(float4*)&av[0]  = *(const float4*)&attn[fi];
  *(float4*)&av[4]  = *(const float4*)&attn[fi + 4];
  int e = row_beg[v];
  const int end = row_end[v];
  float m = -3.4e38f, sum = 0.f;
  float acc[8];
#pragma unroll
  for (int i = 0; i < 8; ++i) acc[i] = 0.f;
  for (; e + 3 < end; e += 4) {               // 4 edges per iter
    int sA = src_sorted[e],     sB = src_sorted[e + 1];
    int sC = src_sorted[e + 2], sD = src_sorted[e + 3];
    uint4 uA = *(const uint4*)&fsb[(size_t)sA * HD + fi];
    uint4 uB = *(const uint4*)&fsb[(size_t)sB * HD + fi];
    uint4 uC = *(const uint4*)&fsb[(size_t)sC * HD + fi];
    uint4 uD = *(const uint4*)&fsb[(size_t)sD * HD + fi];
    float fA[8], fB[8], fC[8], fD[8];
    fA[0] = __uint_as_float(uA.x << 16); fA[1] = __uint_as_float(uA.x & 0xffff0000u);
    fA[2] = __uint_as_float(uA.y << 16); fA[3] = __uint_as_float(uA.y & 0xffff0000u);
    fA[4] = __uint_as_float(uA.z << 16); fA[5] = __uint_as_float(uA.z & 0xffff0000u);
    fA[6] = __uint_as_float(uA.w << 16); fA[7] = __uint_as_float(uA.w & 0xffff0000u);
    fB[0] = __uint_as_float(uB.x << 16); fB[1] = __uint_as_float(uB.x & 0xffff0000u);
    fB[2] = __uint_as_float(uB.y << 16); fB[3] = __uint_as_float(uB.y & 0xffff0000u);
    fB[4] = __uint_as_float(uB.z << 16); fB[5] = __uint_as_float(uB.z & 0xffff0000u);
    fB[6] = __uint_as_float(uB.w << 16); fB[7] = __uint_as_float(uB.w & 0xffff0000u);
    fC[0] = __uint_as_float(uC.x << 16); fC[1] = __uint_as_float(uC.x & 0xffff0000u);
    fC[2] = __uint_as_float(uC.y << 16); fC[3] = __uint_as_float(uC.y & 0xffff0000u);
    fC[4] = __uint_as_float(uC.z << 16); fC[5] = __uint_as_float(uC.z & 0xffff0000u);
    fC[6] = __uint_as_float(uC.w << 16); fC[7] = __uint_as_float(uC.w & 0xffff0000u);
    fD[0] = __uint_as_float(uD.x << 16); fD[1] = __uint_as_float(uD.x & 0xffff0000u);
    fD[2] = __uint_as_float(uD.y << 16); fD[3] = __uint_as_float(uD.y & 0xffff0000u);
    fD[4] = __uint_as_float(uD.z << 16); fD[5] = __uint_as_float(uD.z & 0xffff0000u);
    fD[6] = __uint_as_float(uD.w << 16); fD[7] = __uint_as_float(uD.w & 0xffff0000u);
    float pA = 0.f, pB = 0.f, pC = 0.f, pD = 0.f;
#pragma unroll
    for (int i = 0; i < 8; ++i) {
      float xA = fA[i] + fdv[i];
      pA = fmaf(av[i], fmaxf(xA, 0.f) + 0.2f * fminf(xA, 0.f), pA);
      float xB = fB[i] + fdv[i];
      pB = fmaf(av[i], fmaxf(xB, 0.f) + 0.2f * fminf(xB, 0.f), pB);
      float xC = fC[i] + fdv[i];
      pC = fmaf(av[i], fmaxf(xC, 0.f) + 0.2f * fminf(xC, 0.f), pC);
      float xD = fD[i] + fdv[i];
      pD = fmaf(av[i], fmaxf(xD, 0.f) + 0.2f * fminf(xD, 0.f), pD);
    }
    pA += swz<0x041F>(pA); pB += swz<0x041F>(pB); pC += swz<0x041F>(pC); pD += swz<0x041F>(pD);
    pA += swz<0x081F>(pA); pB += swz<0x081F>(pB); pC += swz<0x081F>(pC); pD += swz<0x081F>(pD);
    pA += swz<0x101F>(pA); pB += swz<0x101F>(pB); pC += swz<0x101F>(pC); pD += swz<0x101F>(pD);
    float mn = fmaxf(fmaxf(m, fmaxf(pA, pB)), fmaxf(pC, pD));
    float scale = __expf(m - mn);
    float wA = __expf(pA - mn), wB = __expf(pB - mn);
    float wC = __expf(pC - mn), wD = __expf(pD - mn);
    sum = fmaf(sum, scale, (wA + wB) + (wC + wD));
#pragma unroll
    for (int i = 0; i < 8; ++i)
      acc[i] = fmaf(acc[i], scale,
                    fmaf(wA, fA[i], fmaf(wB, fB[i], fmaf(wC, fC[i], wD * fD[i]))));
    m = mn;
  }
  for (; e < end; ++e) {                      // 0-3 tail edges (wave-uniform)
    int sA = src_sorted[e];
    uint4 uA = *(const uint4*)&fsb[(size_t)sA * HD + fi];
    float fA[8];
    fA[0] = __uint_as_float(uA.x << 16); fA[1] = __uint_as_float(uA.x & 0xffff0000u);
    fA[2] = __uint_as_float(uA.y << 16); fA[3] = __uint_as_float(uA.y & 0xffff0000u);
    fA[4] = __uint_as_float(uA.z << 16); fA[5] = __uint_as_float(uA.z & 0xffff0000u);
    fA[6] = __uint_as_float(uA.w << 16); fA[7] = __uint_as_float(uA.w & 0xffff0000u);
    float pA = 0.f;
#pragma unroll
    for (int i = 0; i < 8; ++i) {
      float xA = fA[i] + fdv[i];
      pA = fmaf(av[i], fmaxf(xA, 0.f) + 0.2f * fminf(xA, 0.f), pA);
    }
    pA += swz<0x041F>(pA);
    pA += swz<0x081F>(pA);
    pA += swz<0x101F>(pA);
    float mn = fmaxf(m, pA);
    float scale = __expf(m - mn);
    float wA = __expf(pA - mn);
    sum = fmaf(sum, scale, wA);
#pragma unroll
    for (int i = 0; i < 8; ++i)
      acc[i] = fmaf(acc[i], scale, wA * fA[i]);
    m = mn;
  }
  float inv = 1.f / fmaxf(sum, 1e-9f);
  float outv[8];
#pragma unroll
  for (int i = 0; i < 8; ++i) outv[i] = fmaf(acc[i], inv, bias[fi + i]);
  // head-mean: sum across stride-8 lanes (same feat class), then /8
#pragma unroll
  for (int i = 0; i < 8; ++i) {
    outv[i] += swz<0x201F>(outv[i]);          // xor 8
    outv[i] += swz<0x401F>(outv[i]);          // xor 16
    outv[i] += __shfl_xor(outv[i], 32);
    outv[i] *= 0.125f;
    if (do_relu) outv[i] = fmaxf(outv[i], 0.f);
  }
  if (lane < 8) {                             // lane c holds feats 8c..8c+7
    *(float4*)&hout[(size_t)v * DH + lane * 8]     = make_float4(outv[0], outv[1], outv[2], outv[3]);
    *(float4*)&hout[(size_t)v * DH + lane * 8 + 4] = make_float4(outv[4], outv[5], outv[6], outv[7]);
  }
}

// ---------- per-graph mean + MLP head + softmax ----------
__global__ __launch_bounds__(256) void k_head(const float* __restrict__ h2,
    const int* __restrict__ gsv, const float* __restrict__ Wh1,
    const float* __restrict__ bh1, const float* __restrict__ Wh2,
    const float* __restrict__ bh2, float* __restrict__ out) {
  __shared__ float part[4][DH];
  __shared__ float hg[DH];
  __shared__ float hid[DH];
  __shared__ float logits[NC];
  const int g = blockIdx.x;
  const int t = threadIdx.x;
  const int f = t & 63, chunk = t >> 6;
  int start = gsv[g], stop = gsv[g + 1];
  float s = 0.f;
  for (int r = start + chunk; r < stop; r += 4) s += h2[(size_t)r * DH + f];
  part[chunk][f] = s;
  __syncthreads();
  if (t < DH) {
    float tot = part[0][t] + part[1][t] + part[2][t] + part[3][t];
    hg[t] = tot / fmaxf((float)(stop - start), 1.f);
  }
  __syncthreads();
  if (t < DH) {
    float a = 0.f;
    for (int k = 0; k < DH; ++k) a += hg[k] * Wh1[k * DH + t];
    hid[t] = fmaxf(a + bh1[t], 0.f);
  }
  __syncthreads();
  if (t < NC) {
    float l = 0.f;
    for (int k = 0; k < DH; ++k) l += hid[k] * Wh2[k * NC + t];
    logits[t] = l + bh2[t];
  }
  __syncthreads();
  if (t == 0) {
    float mx = logits[0];
    for (int i = 1; i < NC; ++i) mx = fmaxf(mx, logits[i]);
    float sm = 0.f;
    for (int i = 0; i < NC; ++i) {
      float wv = __expf(logits[i] - mx);
      logits[i] = wv;
      sm += wv;
    }
    float inv = 1.f / sm;
    for (int i = 0; i < NC; ++i) out[g * NC + i] = logits[i] * inv;
  }
}

extern "C" void kernel_launch(void* const* d_in, const int* in_sizes, int n_in,
                              void* d_out, int out_size, void* d_ws, size_t ws_size,
                              hipStream_t stream) {
  const float* g_feats = (const float*)d_in[0];
  const int*   src     = (const int*)d_in[1];
  const int*   dst     = (const int*)d_in[2];
  const int*   gid     = (const int*)d_in[3];
  const float* W_in    = (const float*)d_in[4];
  const float* b_in    = (const float*)d_in[5];
  const float* Wsrc1   = (const float*)d_in[6];
  const float* bsrc1   = (const float*)d_in[7];
  const float* Wdst1   = (const float*)d_in[8];
  const float* bdst1   = (const float*)d_in[9];
  const float* attn1   = (const float*)d_in[10];
  const float* bias1   = (const float*)d_in[11];
  const float* Wsrc2   = (const float*)d_in[12];
  const float* bsrc2   = (const float*)d_in[13];
  const float* Wdst2   = (const float*)d_in[14];
  const float* bdst2   = (const float*)d_in[15];
  const float* attn2   = (const float*)d_in[16];
  const float* bias2   = (const float*)d_in[17];
  const float* Wh1     = (const float*)d_in[18];
  const float* bh1     = (const float*)d_in[19];
  const float* Wh2     = (const float*)d_in[20];
  const float* bh2     = (const float*)d_in[21];

  char* ws = (char*)d_ws;
  size_t off = 0;
  auto A = [&](size_t bytes) -> char* {
    char* q = ws + off;
    off = (off + bytes + 255) & ~(size_t)255;
    return q;
  };
  float*    h0         = (float*)A((size_t)NN * DH * 4);
  float*    h1         = (float*)A((size_t)NN * DH * 4);
  float*    h2         = (float*)A((size_t)NN * DH * 4);
  ushort_t* fsb        = (ushort_t*)A((size_t)NN * HD * 2);
  float*    fd         = (float*)A((size_t)NN * HD * 4);
  int*      row_beg    = (int*)A((size_t)NN * 4);
  int*      row_end    = (int*)A((size_t)NN * 4);
  int*      cursor     = (int*)A((size_t)NN * 4);
  int*      src_sorted = (int*)A((size_t)NE * 4);
  int*      gs         = (int*)A((size_t)(NG + 1) * 4);
  int*      counts     = (int*)A((size_t)(NN + 1) * 4);  // +1: gcounter at [NN]

  const int NB_IN = NN / 16;                  // 1250
  const int histb = NE / 256;                 // 1250
  const int gbb = (NN + 256) / 256;           // 79
  const int scatb = NE / 512;                 // 625

  hipMemsetAsync(counts, 0, (size_t)(NN + 1) * 4, stream);

  k_pre<<<NB_IN + histb + gbb, 256, 0, stream>>>(g_feats, W_in, b_in, h0,
                                                 dst, counts, gid, gs);
  k_assign<<<(NN + 255) / 256, 256, 0, stream>>>(counts, row_beg, row_end,
                                                 cursor, &counts[NN]);
  k_scatpair<<<2 * TPM + scatb, 512, 0, stream>>>(h0, Wsrc1, bsrc1, Wdst1, bdst1,
                                                  fsb, fd, dst, src, cursor, src_sorted);
  k_gat<<<NN / 4, 256, 0, stream>>>(fsb, fd, src_sorted, row_beg, row_end,
                                    attn1, bias1, h1, 1);
  k_pair<<<2 * TPM, 512, 0, stream>>>(h1, Wsrc2, bsrc2, Wdst2, bdst2, fsb, fd);
  k_gat<<<NN / 4, 256, 0, stream>>>(fsb, fd, src_sorted, row_beg, row_end,
                                    attn2, bias2, h2, 0);
  k_head<<<NG, 256, 0, stream>>>(h2, gs, Wh1, bh1, Wh2, bh2, (float*)d_out);
}

// Round 15
// 333.687 us; speedup vs baseline: 1.1434x; 1.0556x over previous
//
#include <hip/hip_runtime.h>

#define NN 20000     // nodes
#define NE 320000    // edges
#define NG 64        // graphs
#define DIN 128
#define DH 64
#define NH 8
#define HD 512       // NH*DH
#define NC 32

typedef unsigned short ushort_t;
typedef unsigned int uint_t;

__device__ __forceinline__ ushort_t f2bf(float f) {   // RNE float->bf16
  uint_t x = __float_as_uint(f);
  uint_t r = (x + 0x7fffu + ((x >> 16) & 1u)) >> 16;
  return (ushort_t)r;
}

template<int PAT>
__device__ __forceinline__ float swz(float v) {
  return __int_as_float(__builtin_amdgcn_ds_swizzle(__float_as_int(v), PAT));
}

// ---------- input linear tile: 16 rows of [NN,128]@[128,64]+b (256 thr) ----------
__device__ __forceinline__ void gemm_in_tile(const float* __restrict__ gf,
    const float* __restrict__ W_in, const float* __restrict__ b_in,
    float* __restrict__ h0, int tile) {
  __shared__ float AsIn[16][DIN];
  const int t = threadIdx.x;
  const int row0 = tile * 16;                 // 1250*16 == 20000 exact
  for (int i = t; i < 16 * DIN; i += 256)
    AsIn[i >> 7][i & 127] = gf[(size_t)(row0 + (i >> 7)) * DIN + (i & 127)];
  __syncthreads();
  const int c = t & 63, rg = t >> 6;          // 4 rows per thread
  float acc[4] = {0.f, 0.f, 0.f, 0.f};
  for (int k = 0; k < DIN; ++k) {
    float w = W_in[k * DH + c];
#pragma unroll
    for (int i = 0; i < 4; ++i) acc[i] += AsIn[rg * 4 + i][k] * w;
  }
  float b = b_in[c];
#pragma unroll
  for (int i = 0; i < 4; ++i)
    h0[(size_t)(row0 + rg * 4 + i) * DH + c] = acc[i] + b;
}

// ---------- hidden linear MERGED tile: 16 rows x 512 cols, fs AND fd ------------
// R11's proven 16x512 structure, but one block computes BOTH matrices from one
// A-stripe: per k -> 8 shared LDS reads, 2 independent W float4 loads (2x MLP),
// 64 FMAs. 1250 stripes total.
#define NSTRIPE 1250                          // 20000/16
__device__ __forceinline__ void pair_tile_both(const float* __restrict__ A,
    const float* __restrict__ Ws, const float* __restrict__ bs,
    const float* __restrict__ Wd, const float* __restrict__ bd,
    ushort_t* __restrict__ fsb, float* __restrict__ fd, int stripe) {
  __shared__ float AsP[16][DH];               // 4 KB
  const int t = threadIdx.x;                  // 0..255
  const int row0 = stripe * 16;
  {                                           // stage 16x64 floats as float4
    int idx = t * 4;
    int r = idx >> 6, k = idx & 63;
    *(float4*)&AsP[r][k] = *(const float4*)&A[(size_t)(row0 + r) * DH + k];
  }
  __syncthreads();
  const int tc = t & 127;                     // col quad: cols 4tc..4tc+3
  const int tr = t >> 7;                      // rows tr*8 .. tr*8+7
  float accS[8][4], accD[8][4];
#pragma unroll
  for (int r = 0; r < 8; ++r)
#pragma unroll
    for (int c = 0; c < 4; ++c) { accS[r][c] = 0.f; accD[r][c] = 0.f; }
#pragma unroll 4
  for (int k = 0; k < DH; ++k) {
    float4 ws4 = *(const float4*)&Ws[(size_t)k * HD + 4 * tc];
    float4 wd4 = *(const float4*)&Wd[(size_t)k * HD + 4 * tc];
#pragma unroll
    for (int r = 0; r < 8; ++r) {
      float a = AsP[tr * 8 + r][k];
      accS[r][0] = fmaf(a, ws4.x, accS[r][0]);
      accS[r][1] = fmaf(a, ws4.y, accS[r][1]);
      accS[r][2] = fmaf(a, ws4.z, accS[r][2]);
      accS[r][3] = fmaf(a, ws4.w, accS[r][3]);
      accD[r][0] = fmaf(a, wd4.x, accD[r][0]);
      accD[r][1] = fmaf(a, wd4.y, accD[r][1]);
      accD[r][2] = fmaf(a, wd4.z, accD[r][2]);
      accD[r][3] = fmaf(a, wd4.w, accD[r][3]);
    }
  }
  float4 bsv = *(const float4*)&bs[4 * tc];
  float4 bdv = *(const float4*)&bd[4 * tc];
#pragma unroll
  for (int r = 0; r < 8; ++r) {
    int row = row0 + tr * 8 + r;              // 20000 % 16 == 0, in range
    ushort4 o;
    o.x = f2bf(accS[r][0] + bsv.x); o.y = f2bf(accS[r][1] + bsv.y);
    o.z = f2bf(accS[r][2] + bsv.z); o.w = f2bf(accS[r][3] + bsv.w);
    *(ushort4*)&fsb[(size_t)row * HD + 4 * tc] = o;
    *(float4*)&fd[(size_t)row * HD + 4 * tc] =
        make_float4(accD[r][0] + bdv.x, accD[r][1] + bdv.y,
                    accD[r][2] + bdv.z, accD[r][3] + bdv.w);
  }
}

// ---------- P0: blocks 0..1249 input GEMM | 1250..2499 hist | 2500.. gbound ------
__global__ __launch_bounds__(256) void k_pre(const float* __restrict__ gf,
    const float* __restrict__ W_in, const float* __restrict__ b_in,
    float* __restrict__ h0, const int* __restrict__ dst, int* __restrict__ counts,
    const int* __restrict__ gid, int* __restrict__ gs) {
  const int bid = blockIdx.x;
  const int NB_IN = NN / 16;                  // 1250
  if (bid < NB_IN) {
    gemm_in_tile(gf, W_in, b_in, h0, bid);
  } else if (bid < NB_IN + NE / 256) {
    int e = (bid - NB_IN) * 256 + threadIdx.x;
    atomicAdd(&counts[dst[e]], 1);
  } else {
    int i = (bid - (NB_IN + NE / 256)) * 256 + threadIdx.x;
    if (i > NN) return;
    if (i == 0) {
      for (int g = 0; g <= gid[0]; ++g) gs[g] = 0;
    } else if (i == NN) {
      for (int g = gid[NN - 1] + 1; g <= NG; ++g) gs[g] = NN;
    } else {
      int a = gid[i - 1], b2 = gid[i];
      for (int g = a + 1; g <= b2; ++g) gs[g] = i;
    }
  }
}

// ---------- parallel CSR segment assignment (wave scan + 1 atomic/wave) ----------
__global__ __launch_bounds__(256) void k_assign(const int* __restrict__ counts,
    int* __restrict__ row_beg, int* __restrict__ row_end, int* __restrict__ cursor,
    int* __restrict__ gcounter) {
  const int i = blockIdx.x * 256 + threadIdx.x;
  const int lane = threadIdx.x & 63;
  int cnt = (i < NN) ? counts[i] : 0;
  int pre = cnt;                              // inclusive scan over 64 lanes
#pragma unroll
  for (int d = 1; d < 64; d <<= 1) {
    int o = __shfl_up(pre, d);
    if (lane >= d) pre += o;
  }
  int total = __shfl(pre, 63);
  int excl = pre - cnt;
  int base = 0;
  if (lane == 63 && total > 0) base = atomicAdd(gcounter, total);
  base = __shfl(base, 63);
  if (i < NN) {
    int b = base + excl;
    row_beg[i] = b;
    row_end[i] = b + cnt;
    cursor[i] = b;
  }
}

// ---------- P3: blocks 0..1249 layer-1 merged GEMM | 1250..2499 CSR scatter ------
__global__ __launch_bounds__(256) void k_scatpair(const float* __restrict__ A,
    const float* __restrict__ Ws, const float* __restrict__ bs,
    const float* __restrict__ Wd, const float* __restrict__ bd,
    ushort_t* __restrict__ fsb, float* __restrict__ fd,
    const int* __restrict__ dst, const int* __restrict__ src,
    int* __restrict__ cursor, int* __restrict__ src_sorted) {
  const int bid = blockIdx.x;
  if (bid < NSTRIPE) {
    pair_tile_both(A, Ws, bs, Wd, bd, fsb, fd, bid);
  } else {
    int e = (bid - NSTRIPE) * 256 + threadIdx.x;
    int p = atomicAdd(&cursor[dst[e]], 1);
    src_sorted[p] = src[e];
  }
}

// ---------- layer-2 merged GEMM ----------
__global__ __launch_bounds__(256) void k_pair(const float* __restrict__ A,
    const float* __restrict__ Ws, const float* __restrict__ bs,
    const float* __restrict__ Wd, const float* __restrict__ bd,
    ushort_t* __restrict__ fsb, float* __restrict__ fd) {
  pair_tile_both(A, Ws, bs, Wd, bd, fsb, fd, blockIdx.x);
}

// ---------- fused GATv2: ONE WAVE PER NODE, lane = 8 contiguous bf16 feats --------
// 4-edge unroll: shared online-softmax rescale + 4 outstanding gathers.
__global__ __launch_bounds__(256) void k_gat(const ushort_t* __restrict__ fsb,
    const float* __restrict__ fd, const int* __restrict__ src_sorted,
    const int* __restrict__ row_beg, const int* __restrict__ row_end,
    const float* __restrict__ attn, const float* __restrict__ bias,
    float* __restrict__ hout, int do_relu) {
  const int lane = threadIdx.x & 63;
  const int v = blockIdx.x * 4 + (threadIdx.x >> 6);
  const int fi = lane * 8;                    // head = lane>>3
  float fdv[8], av[8];
  *(float4*)&fdv[0] = *(const float4*)&fd[(size_t)v * HD + fi];
  *(float4*)&fdv[4] = *(const float4*)&fd[(size_t)v * HD + fi + 4];
  *(float4*)&av[0]  = *(const float4*)&attn[fi];
  *(float4*)&av[4]  = *(const float4*)&attn[fi + 4];
  int e = row_beg[v];
  const int end = row_end[v];
  float m = -3.4e38f, sum = 0.f;
  float acc[8];
#pragma unroll
  for (int i = 0; i < 8; ++i) acc[i] = 0.f;
  for (; e + 3 < end; e += 4) {               // 4 edges per iter
    int sA = src_sorted[e],     sB = src_sorted[e + 1];
    int sC = src_sorted[e + 2], sD = src_sorted[e + 3];
    uint4 uA = *(const uint4*)&fsb[(size_t)sA * HD + fi];
    uint4 uB = *(const uint4*)&fsb[(size_t)sB * HD + fi];
    uint4 uC = *(const uint4*)&fsb[(size_t)sC * HD + fi];
    uint4 uD = *(const uint4*)&fsb[(size_t)sD * HD + fi];
    float fA[8], fB[8], fC[8], fD[8];
    fA[0] = __uint_as_float(uA.x << 16); fA[1] = __uint_as_float(uA.x & 0xffff0000u);
    fA[2] = __uint_as_float(uA.y << 16); fA[3] = __uint_as_float(uA.y & 0xffff0000u);
    fA[4] = __uint_as_float(uA.z << 16); fA[5] = __uint_as_float(uA.z & 0xffff0000u);
    fA[6] = __uint_as_float(uA.w << 16); fA[7] = __uint_as_float(uA.w & 0xffff0000u);
    fB[0] = __uint_as_float(uB.x << 16); fB[1] = __uint_as_float(uB.x & 0xffff0000u);
    fB[2] = __uint_as_float(uB.y << 16); fB[3] = __uint_as_float(uB.y & 0xffff0000u);
    fB[4] = __uint_as_float(uB.z << 16); fB[5] = __uint_as_float(uB.z & 0xffff0000u);
    fB[6] = __uint_as_float(uB.w << 16); fB[7] = __uint_as_float(uB.w & 0xffff0000u);
    fC[0] = __uint_as_float(uC.x << 16); fC[1] = __uint_as_float(uC.x & 0xffff0000u);
    fC[2] = __uint_as_float(uC.y << 16); fC[3] = __uint_as_float(uC.y & 0xffff0000u);
    fC[4] = __uint_as_float(uC.z << 16); fC[5] = __uint_as_float(uC.z & 0xffff0000u);
    fC[6] = __uint_as_float(uC.w << 16); fC[7] = __uint_as_float(uC.w & 0xffff0000u);
    fD[0] = __uint_as_float(uD.x << 16); fD[1] = __uint_as_float(uD.x & 0xffff0000u);
    fD[2] = __uint_as_float(uD.y << 16); fD[3] = __uint_as_float(uD.y & 0xffff0000u);
    fD[4] = __uint_as_float(uD.z << 16); fD[5] = __uint_as_float(uD.z & 0xffff0000u);
    fD[6] = __uint_as_float(uD.w << 16); fD[7] = __uint_as_float(uD.w & 0xffff0000u);
    float pA = 0.f, pB = 0.f, pC = 0.f, pD = 0.f;
#pragma unroll
    for (int i = 0; i < 8; ++i) {
      float xA = fA[i] + fdv[i];
      pA = fmaf(av[i], fmaxf(xA, 0.f) + 0.2f * fminf(xA, 0.f), pA);
      float xB = fB[i] + fdv[i];
      pB = fmaf(av[i], fmaxf(xB, 0.f) + 0.2f * fminf(xB, 0.f), pB);
      float xC = fC[i] + fdv[i];
      pC = fmaf(av[i], fmaxf(xC, 0.f) + 0.2f * fminf(xC, 0.f), pC);
      float xD = fD[i] + fdv[i];
      pD = fmaf(av[i], fmaxf(xD, 0.f) + 0.2f * fminf(xD, 0.f), pD);
    }
    pA += swz<0x041F>(pA); pB += swz<0x041F>(pB); pC += swz<0x041F>(pC); pD += swz<0x041F>(pD);
    pA += swz<0x081F>(pA); pB += swz<0x081F>(pB); pC += swz<0x081F>(pC); pD += swz<0x081F>(pD);
    pA += swz<0x101F>(pA); pB += swz<0x101F>(pB); pC += swz<0x101F>(pC); pD += swz<0x101F>(pD);
    float mn = fmaxf(fmaxf(m, fmaxf(pA, pB)), fmaxf(pC, pD));
    float scale = __expf(m - mn);
    float wA = __expf(pA - mn), wB = __expf(pB - mn);
    float wC = __expf(pC - mn), wD = __expf(pD - mn);
    sum = fmaf(sum, scale, (wA + wB) + (wC + wD));
#pragma unroll
    for (int i = 0; i < 8; ++i)
      acc[i] = fmaf(acc[i], scale,
                    fmaf(wA, fA[i], fmaf(wB, fB[i], fmaf(wC, fC[i], wD * fD[i]))));
    m = mn;
  }
  for (; e < end; ++e) {                      // 0-3 tail edges (wave-uniform)
    int sA = src_sorted[e];
    uint4 uA = *(const uint4*)&fsb[(size_t)sA * HD + fi];
    float fA[8];
    fA[0] = __uint_as_float(uA.x << 16); fA[1] = __uint_as_float(uA.x & 0xffff0000u);
    fA[2] = __uint_as_float(uA.y << 16); fA[3] = __uint_as_float(uA.y & 0xffff0000u);
    fA[4] = __uint_as_float(uA.z << 16); fA[5] = __uint_as_float(uA.z & 0xffff0000u);
    fA[6] = __uint_as_float(uA.w << 16); fA[7] = __uint_as_float(uA.w & 0xffff0000u);
    float pA = 0.f;
#pragma unroll
    for (int i = 0; i < 8; ++i) {
      float xA = fA[i] + fdv[i];
      pA = fmaf(av[i], fmaxf(xA, 0.f) + 0.2f * fminf(xA, 0.f), pA);
    }
    pA += swz<0x041F>(pA);
    pA += swz<0x081F>(pA);
    pA += swz<0x101F>(pA);
    float mn = fmaxf(m, pA);
    float scale = __expf(m - mn);
    float wA = __expf(pA - mn);
    sum = fmaf(sum, scale, wA);
#pragma unroll
    for (int i = 0; i < 8; ++i)
      acc[i] = fmaf(acc[i], scale, wA * fA[i]);
    m = mn;
  }
  float inv = 1.f / fmaxf(sum, 1e-9f);
  float outv[8];
#pragma unroll
  for (int i = 0; i < 8; ++i) outv[i] = fmaf(acc[i], inv, bias[fi + i]);
  // head-mean: sum across stride-8 lanes (same feat class), then /8
#pragma unroll
  for (int i = 0; i < 8; ++i) {
    outv[i] += swz<0x201F>(outv[i]);          // xor 8
    outv[i] += swz<0x401F>(outv[i]);          // xor 16
    outv[i] += __shfl_xor(outv[i], 32);
    outv[i] *= 0.125f;
    if (do_relu) outv[i] = fmaxf(outv[i], 0.f);
  }
  if (lane < 8) {                             // lane c holds feats 8c..8c+7
    *(float4*)&hout[(size_t)v * DH + lane * 8]     = make_float4(outv[0], outv[1], outv[2], outv[3]);
    *(float4*)&hout[(size_t)v * DH + lane * 8 + 4] = make_float4(outv[4], outv[5], outv[6], outv[7]);
  }
}

// ---------- per-graph mean + MLP head + softmax ----------
__global__ __launch_bounds__(256) void k_head(const float* __restrict__ h2,
    const int* __restrict__ gsv, const float* __restrict__ Wh1,
    const float* __restrict__ bh1, const float* __restrict__ Wh2,
    const float* __restrict__ bh2, float* __restrict__ out) {
  __shared__ float part[4][DH];
  __shared__ float hg[DH];
  __shared__ float hid[DH];
  __shared__ float logits[NC];
  const int g = blockIdx.x;
  const int t = threadIdx.x;
  const int f = t & 63, chunk = t >> 6;
  int start = gsv[g], stop = gsv[g + 1];
  float s = 0.f;
  for (int r = start + chunk; r < stop; r += 4) s += h2[(size_t)r * DH + f];
  part[chunk][f] = s;
  __syncthreads();
  if (t < DH) {
    float tot = part[0][t] + part[1][t] + part[2][t] + part[3][t];
    hg[t] = tot / fmaxf((float)(stop - start), 1.f);
  }
  __syncthreads();
  if (t < DH) {
    float a = 0.f;
    for (int k = 0; k < DH; ++k) a += hg[k] * Wh1[k * DH + t];
    hid[t] = fmaxf(a + bh1[t], 0.f);
  }
  __syncthreads();
  if (t < NC) {
    float l = 0.f;
    for (int k = 0; k < DH; ++k) l += hid[k] * Wh2[k * NC + t];
    logits[t] = l + bh2[t];
  }
  __syncthreads();
  if (t == 0) {
    float mx = logits[0];
    for (int i = 1; i < NC; ++i) mx = fmaxf(mx, logits[i]);
    float sm = 0.f;
    for (int i = 0; i < NC; ++i) {
      float wv = __expf(logits[i] - mx);
      logits[i] = wv;
      sm += wv;
    }
    float inv = 1.f / sm;
    for (int i = 0; i < NC; ++i) out[g * NC + i] = logits[i] * inv;
  }
}

extern "C" void kernel_launch(void* const* d_in, const int* in_sizes, int n_in,
                              void* d_out, int out_size, void* d_ws, size_t ws_size,
                              hipStream_t stream) {
  const float* g_feats = (const float*)d_in[0];
  const int*   src     = (const int*)d_in[1];
  const int*   dst     = (const int*)d_in[2];
  const int*   gid     = (const int*)d_in[3];
  const float* W_in    = (const float*)d_in[4];
  const float* b_in    = (const float*)d_in[5];
  const float* Wsrc1   = (const float*)d_in[6];
  const float* bsrc1   = (const float*)d_in[7];
  const float* Wdst1   = (const float*)d_in[8];
  const float* bdst1   = (const float*)d_in[9];
  const float* attn1   = (const float*)d_in[10];
  const float* bias1   = (const float*)d_in[11];
  const float* Wsrc2   = (const float*)d_in[12];
  const float* bsrc2   = (const float*)d_in[13];
  const float* Wdst2   = (const float*)d_in[14];
  const float* bdst2   = (const float*)d_in[15];
  const float* attn2   = (const float*)d_in[16];
  const float* bias2   = (const float*)d_in[17];
  const float* Wh1     = (const float*)d_in[18];
  const float* bh1     = (const float*)d_in[19];
  const float* Wh2     = (const float*)d_in[20];
  const float* bh2     = (const float*)d_in[21];

  char* ws = (char*)d_ws;
  size_t off = 0;
  auto A = [&](size_t bytes) -> char* {
    char* q = ws + off;
    off = (off + bytes + 255) & ~(size_t)255;
    return q;
  };
  float*    h0         = (float*)A((size_t)NN * DH * 4);
  float*    h1         = (float*)A((size_t)NN * DH * 4);
  float*    h2         = (float*)A((size_t)NN * DH * 4);
  ushort_t* fsb        = (ushort_t*)A((size_t)NN * HD * 2);
  float*    fd         = (float*)A((size_t)NN * HD * 4);
  int*      row_beg    = (int*)A((size_t)NN * 4);
  int*      row_end    = (int*)A((size_t)NN * 4);
  int*      cursor     = (int*)A((size_t)NN * 4);
  int*      src_sorted = (int*)A((size_t)NE * 4);
  int*      gs         = (int*)A((size_t)(NG + 1) * 4);
  int*      counts     = (int*)A((size_t)(NN + 1) * 4);  // +1: gcounter at [NN]

  const int NB_IN = NN / 16;                  // 1250
  const int histb = NE / 256;                 // 1250
  const int gbb = (NN + 256) / 256;           // 79

  hipMemsetAsync(counts, 0, (size_t)(NN + 1) * 4, stream);

  k_pre<<<NB_IN + histb + gbb, 256, 0, stream>>>(g_feats, W_in, b_in, h0,
                                                 dst, counts, gid, gs);
  k_assign<<<(NN + 255) / 256, 256, 0, stream>>>(counts, row_beg, row_end,
                                                 cursor, &counts[NN]);
  k_scatpair<<<NSTRIPE + histb, 256, 0, stream>>>(h0, Wsrc1, bsrc1, Wdst1, bdst1,
                                                  fsb, fd, dst, src, cursor, src_sorted);
  k_gat<<<NN / 4, 256, 0, stream>>>(fsb, fd, src_sorted, row_beg, row_end,
                                    attn1, bias1, h1, 1);
  k_pair<<<NSTRIPE, 256, 0, stream>>>(h1, Wsrc2, bsrc2, Wdst2, bdst2, fsb, fd);
  k_gat<<<NN / 4, 256, 0, stream>>>(fsb, fd, src_sorted, row_beg, row_end,
                                    attn2, bias2, h2, 0);
  k_head<<<NG, 256, 0, stream>>>(h2, gs, Wh1, bh1, Wh2, bh2, (float*)d_out);
}